// Round 1
// baseline (741.107 us; speedup 1.0000x reference)
//
#include <hip/hip_runtime.h>
#include <stdint.h>

#define B_ 16
#define C_ 768
#define N_ 4096
#define HEADS_ 12

typedef __attribute__((ext_vector_type(4))) float f32x4;
typedef __attribute__((ext_vector_type(8))) short s16x8;

__device__ __forceinline__ ushort f2bf(float f){
  union { float f; uint32_t u; } v; v.f = f;
  uint32_t u = v.u;
  uint32_t r = (u + 0x7fffu + ((u >> 16) & 1u)) >> 16;
  return (ushort)r;
}
__device__ __forceinline__ float bf2f(ushort h){
  union { uint32_t u; float f; } v; v.u = ((uint32_t)h) << 16;
  return v.f;
}

// ---------------- convert fp32 -> bf16 (weights) ----------------
__global__ __launch_bounds__(256) void k_convert(const float* __restrict__ src,
                                                 ushort* __restrict__ dst, int n){
  int i = (blockIdx.x * 256 + threadIdx.x) * 4;
  if (i < n){
    float4 v = *(const float4*)(src + i);
    ushort4 u;
    u.x = f2bf(v.x); u.y = f2bf(v.y); u.z = f2bf(v.z); u.w = f2bf(v.w);
    *(ushort4*)(dst + i) = u;
  }
}

// ---------------- transpose+convert x[b][c][n] -> xT[b][n][c] bf16 ----------------
__global__ __launch_bounds__(256) void k_transpose(const float* __restrict__ x,
                                                   ushort* __restrict__ xT){
  __shared__ ushort tile[64][72];
  int b = blockIdx.z;
  int n0 = blockIdx.x * 64;
  int k0 = blockIdx.y * 64;
  int t = threadIdx.x;
  const float* xb = x + (size_t)b * C_ * N_;
  #pragma unroll
  for (int p = 0; p < 4; ++p){
    int krow = (t >> 4) + p * 16;
    int nn = (t & 15) * 4;
    float4 v = *(const float4*)(xb + (size_t)(k0 + krow) * N_ + n0 + nn);
    tile[nn + 0][krow] = f2bf(v.x);
    tile[nn + 1][krow] = f2bf(v.y);
    tile[nn + 2][krow] = f2bf(v.z);
    tile[nn + 3][krow] = f2bf(v.w);
  }
  __syncthreads();
  ushort* dst = xT + (size_t)b * N_ * C_;
  #pragma unroll
  for (int p = 0; p < 4; ++p){
    int nrow = (t >> 4) + p * 16;
    int kk = (t & 15) * 4;
    ushort4 u = *(ushort4*)&tile[nrow][kk];
    *(ushort4*)(dst + (size_t)(n0 + nrow) * C_ + k0 + kk) = u;
  }
}

// ---------------- GEMM1: w[b][n][c'] = sum_k xT[b][n][k] * Wq[c'][k], + colnorm2 ----
#define BM 128
#define BN 128
#define BK 64
#define LDK 72

__global__ __launch_bounds__(256, 2) void k_gemm1(const ushort* __restrict__ xT,
                                                  const ushort* __restrict__ wq,
                                                  ushort* __restrict__ w,
                                                  float* __restrict__ colnorm2){
  __shared__ ushort As[BM * LDK];
  __shared__ ushort Bs[BN * LDK];
  int b = blockIdx.z;
  int n0 = blockIdx.x * BM;
  int c0 = blockIdx.y * BN;
  int t = threadIdx.x;
  int lane = t & 63, wv = t >> 6;
  int wm = wv >> 1, wn = wv & 1;
  int col = lane & 15, quad = lane >> 4;
  const ushort* Ag = xT + (size_t)b * N_ * C_ + (size_t)n0 * C_;
  const ushort* Bg = wq + (size_t)c0 * C_;
  f32x4 acc[4][4] = {};
  for (int kt = 0; kt < C_; kt += BK){
    #pragma unroll
    for (int p = 0; p < 4; ++p){
      int q = t + 256 * p;
      int row = q >> 3, ch = q & 7;
      uint4 va = *(const uint4*)(Ag + (size_t)row * C_ + kt + ch * 8);
      *(uint4*)&As[row * LDK + ch * 8] = va;
      uint4 vb = *(const uint4*)(Bg + (size_t)row * C_ + kt + ch * 8);
      *(uint4*)&Bs[row * LDK + ch * 8] = vb;
    }
    __syncthreads();
    #pragma unroll
    for (int ks = 0; ks < 2; ++ks){
      s16x8 af[4], bf[4];
      #pragma unroll
      for (int mt = 0; mt < 4; ++mt)
        af[mt] = *(s16x8*)&As[(wm * 64 + mt * 16 + col) * LDK + ks * 32 + quad * 8];
      #pragma unroll
      for (int nt = 0; nt < 4; ++nt)
        bf[nt] = *(s16x8*)&Bs[(wn * 64 + nt * 16 + col) * LDK + ks * 32 + quad * 8];
      #pragma unroll
      for (int mt = 0; mt < 4; ++mt)
        #pragma unroll
        for (int nt = 0; nt < 4; ++nt)
          acc[mt][nt] = __builtin_amdgcn_mfma_f32_16x16x32_bf16(af[mt], bf[nt], acc[mt][nt], 0, 0, 0);
    }
    __syncthreads();
  }
  // epilogue: D[row=n][col=c']; store bf16 w and accumulate column sums of squares
  ushort* wb = w + (size_t)b * N_ * C_;
  #pragma unroll
  for (int nt = 0; nt < 4; ++nt){
    int cc = c0 + wn * 64 + nt * 16 + col;
    float ss = 0.f;
    #pragma unroll
    for (int mt = 0; mt < 4; ++mt){
      #pragma unroll
      for (int r = 0; r < 4; ++r){
        int nn = n0 + wm * 64 + mt * 16 + quad * 4 + r;
        float v = acc[mt][nt][r];
        wb[(size_t)nn * C_ + cc] = f2bf(v);
        ss += v * v;
      }
    }
    ss += __shfl_xor(ss, 16);
    ss += __shfl_xor(ss, 32);
    if (quad == 0) atomicAdd(colnorm2 + b * C_ + cc, ss);
  }
}

// ---------------- stats: softmax over heads, Pi, S, T ----------------
__global__ __launch_bounds__(256) void k_stats(const ushort* __restrict__ w,
                                               const float* __restrict__ colnorm2,
                                               const float* __restrict__ temp,
                                               float* __restrict__ Pi,
                                               float* __restrict__ S,
                                               float* __restrict__ T){
  int b = blockIdx.y;
  int chunk = blockIdx.x;
  int t = threadIdx.x;
  int lane = t & 63, wv = t >> 6;
  float invcn[HEADS_], tmp[HEADS_], S_loc[HEADS_], T_loc[HEADS_];
  #pragma unroll
  for (int j = 0; j < HEADS_; ++j){
    float cn = colnorm2[b * C_ + j * 64 + lane];
    invcn[j] = 1.0f / fmaxf(cn, 1e-24f);
    tmp[j] = temp[j];
    S_loc[j] = 0.f; T_loc[j] = 0.f;
  }
  const ushort* wb = w + (size_t)b * N_ * C_;
  for (int it = 0; it < 64; ++it){
    int n = chunk * 256 + wv * 64 + it;
    const ushort* row = wb + (size_t)n * C_;
    float v[HEADS_], r[HEADS_];
    #pragma unroll
    for (int j = 0; j < HEADS_; ++j){
      float f = bf2f(row[j * 64 + lane]);
      v[j] = f * f;
      r[j] = v[j] * invcn[j];
    }
    #pragma unroll
    for (int j = 0; j < HEADS_; ++j){
      #pragma unroll
      for (int off = 1; off < 64; off <<= 1)
        r[j] += __shfl_xor(r[j], off);
    }
    float m = -1e30f;
    #pragma unroll
    for (int j = 0; j < HEADS_; ++j){ r[j] *= tmp[j]; m = fmaxf(m, r[j]); }
    float se = 0.f, p[HEADS_];
    #pragma unroll
    for (int j = 0; j < HEADS_; ++j){ p[j] = __expf(r[j] - m); se += p[j]; }
    float inv = 1.0f / se;
    #pragma unroll
    for (int j = 0; j < HEADS_; ++j){
      p[j] *= inv;
      S_loc[j] += p[j];
      T_loc[j] += p[j] * v[j];
    }
    if (lane == 0){
      float4* dst = (float4*)(Pi + ((size_t)b * N_ + n) * HEADS_);
      dst[0] = make_float4(p[0], p[1], p[2], p[3]);
      dst[1] = make_float4(p[4], p[5], p[6], p[7]);
      dst[2] = make_float4(p[8], p[9], p[10], p[11]);
    }
  }
  #pragma unroll
  for (int j = 0; j < HEADS_; ++j){
    atomicAdd(T + b * C_ + j * 64 + lane, T_loc[j]);
    if (lane == j) atomicAdd(S + b * HEADS_ + j, S_loc[j]);
  }
}

// ---------------- attn = 1/(1 + T/(S+1e-8)) ----------------
__global__ __launch_bounds__(256) void k_attnfin(const float* __restrict__ S,
                                                 const float* __restrict__ T,
                                                 float* __restrict__ attn){
  int i = blockIdx.x * 256 + threadIdx.x;
  if (i < B_ * C_){
    int b = i / C_, c = i % C_;
    float dots = T[i] / (S[b * HEADS_ + c / 64] + 1e-8f);
    attn[i] = 1.0f / (1.0f + dots);
  }
}

// ---------------- GEMM2: out[b][c'][n] = sum_k Wout[c'][k] * (-w*Pi*attn) ----------
__global__ __launch_bounds__(256, 2) void k_gemm2(const ushort* __restrict__ w,
                                                  const ushort* __restrict__ wout,
                                                  const float* __restrict__ Pi,
                                                  const float* __restrict__ attn,
                                                  float* __restrict__ out){
  __shared__ ushort As[BM * LDK];   // Wout[c'][k]
  __shared__ ushort Bs[BN * LDK];   // scaled w, [n][k]
  int b = blockIdx.z;
  int c0 = blockIdx.x * BM;
  int n0 = blockIdx.y * BN;
  int t = threadIdx.x;
  int lane = t & 63, wv = t >> 6;
  int wm = wv >> 1, wn = wv & 1;
  int col = lane & 15, quad = lane >> 4;
  const ushort* Ag = wout + (size_t)c0 * C_;
  const ushort* Wg = w + (size_t)b * N_ * C_ + (size_t)n0 * C_;
  const float* attn_b = attn + b * C_;
  f32x4 acc[4][4] = {};
  for (int kt = 0; kt < HEADS_; ++kt){       // k0 = kt*64, head = kt
    #pragma unroll
    for (int p = 0; p < 4; ++p){
      int q = t + 256 * p;
      int row = q >> 3, ch = q & 7;
      uint4 va = *(const uint4*)(Ag + (size_t)row * C_ + kt * 64 + ch * 8);
      *(uint4*)&As[row * LDK + ch * 8] = va;
      uint4 vb = *(const uint4*)(Wg + (size_t)row * C_ + kt * 64 + ch * 8);
      float pscale = -Pi[((size_t)b * N_ + n0 + row) * HEADS_ + kt];
      ushort* pv = (ushort*)&vb;
      ushort sc[8];
      #pragma unroll
      for (int i = 0; i < 8; ++i){
        float f = bf2f(pv[i]) * pscale * attn_b[kt * 64 + ch * 8 + i];
        sc[i] = f2bf(f);
      }
      *(uint4*)&Bs[row * LDK + ch * 8] = *(uint4*)sc;
    }
    __syncthreads();
    #pragma unroll
    for (int ks = 0; ks < 2; ++ks){
      s16x8 af[4], bf[4];
      #pragma unroll
      for (int mt = 0; mt < 4; ++mt)
        af[mt] = *(s16x8*)&As[(wm * 64 + mt * 16 + col) * LDK + ks * 32 + quad * 8];
      #pragma unroll
      for (int nt = 0; nt < 4; ++nt)
        bf[nt] = *(s16x8*)&Bs[(wn * 64 + nt * 16 + col) * LDK + ks * 32 + quad * 8];
      #pragma unroll
      for (int mt = 0; mt < 4; ++mt)
        #pragma unroll
        for (int nt = 0; nt < 4; ++nt)
          acc[mt][nt] = __builtin_amdgcn_mfma_f32_16x16x32_bf16(af[mt], bf[nt], acc[mt][nt], 0, 0, 0);
    }
    __syncthreads();
  }
  // epilogue: D[row=c'][col=n] -> out[b][c'][n], lane-coalesced along n
  #pragma unroll
  for (int mt = 0; mt < 4; ++mt){
    #pragma unroll
    for (int nt = 0; nt < 4; ++nt){
      int nn = n0 + wn * 64 + nt * 16 + col;
      #pragma unroll
      for (int r = 0; r < 4; ++r){
        int cc = c0 + wm * 64 + mt * 16 + quad * 4 + r;
        out[((size_t)b * C_ + cc) * N_ + nn] = acc[mt][nt][r];
      }
    }
  }
}

extern "C" void kernel_launch(void* const* d_in, const int* in_sizes, int n_in,
                              void* d_out, int out_size, void* d_ws, size_t ws_size,
                              hipStream_t stream){
  const float* x    = (const float*)d_in[0];
  const float* Wqkv = (const float*)d_in[1];
  const float* Wout = (const float*)d_in[2];
  const float* temp = (const float*)d_in[3];
  float* out = (float*)d_out;
  char* ws = (char*)d_ws;

  const size_t sz_w  = (size_t)B_ * N_ * C_ * sizeof(ushort);   // 100663296
  const size_t sz_wt = (size_t)C_ * C_ * sizeof(ushort);        // 1179648

  ushort* w_buf = (ushort*)ws;
  ushort* wq_b  = (ushort*)(ws + sz_w);
  ushort* wo_b  = (ushort*)(ws + sz_w + sz_wt);
  float*  colnorm2 = (float*)(ws + sz_w + 2 * sz_wt);
  float*  S_ = colnorm2 + B_ * C_;
  float*  T_ = S_ + B_ * HEADS_;
  float*  Pi = T_ + B_ * C_;
  float*  attn = Pi + (size_t)B_ * N_ * HEADS_;
  // xT lives in d_out (dead before GEMM2 writes d_out)
  ushort* xT = (ushort*)d_out;

  // zero colnorm2 + S + T (contiguous)
  hipMemsetAsync(colnorm2, 0, (size_t)(2 * B_ * C_ + B_ * HEADS_) * sizeof(float), stream);

  k_convert<<<576, 256, 0, stream>>>(Wqkv, wq_b, C_ * C_);
  k_convert<<<576, 256, 0, stream>>>(Wout, wo_b, C_ * C_);
  k_transpose<<<dim3(N_ / 64, C_ / 64, B_), 256, 0, stream>>>(x, xT);
  k_gemm1<<<dim3(N_ / BM, C_ / BN, B_), 256, 0, stream>>>(xT, wq_b, w_buf, colnorm2);
  k_stats<<<dim3(16, B_), 256, 0, stream>>>(w_buf, colnorm2, temp, Pi, S_, T_);
  k_attnfin<<<48, 256, 0, stream>>>(S_, T_, attn);
  k_gemm2<<<dim3(C_ / BM, N_ / BN, B_), 256, 0, stream>>>(w_buf, wo_b, Pi, attn, out);
}